// Round 7
// baseline (419.580 us; speedup 1.0000x reference)
//
#include <hip/hip_runtime.h>

// PointConv fused kernel for MI355X (gfx950).
// B=1, N=200000, K=16, C_IN=3, C_MID=16, HIDDEN=[8,8], LAST_CH=6, C_OUT=64.
// One thread per point: gather 16 neighbors, run WeightNet (3->8->8->16 MLP with
// folded BN-affine), accumulate feat^T @ weights outer products into acc[96],
// then final 96x64 linear + ReLU. All weights are thread-uniform -> compiler
// scalarizes to s_load + SGPR operands (VALU-bound design, LDS unused).
// R1: weightNetInput buffered in registers, stored as 12x float4 post-loop.
// R2: non-temporal stores for both outputs (write-once data; keep L2 for the
//     random xyz/feats gathers, which exceed one XCD's 4 MiB L2).
// R3: N derived from in_sizes (robustness).
// R5: FIX compile error — __builtin_nontemporal_store requires a NATIVE vector
//     pointer; HIP float4 is a class. Use ext_vector_type(4) float instead.
// R6: resubmission of R5 unchanged (broker timeout; kernel has never run).

constexpr int K     = 16;
constexpr int C_OUT = 64;

typedef float f32x4 __attribute__((ext_vector_type(4)));

__global__ __launch_bounds__(256, 2) void pointconv_fused(
    const float* __restrict__ xyz,    // [N,3]
    const float* __restrict__ feats,  // [N,3]
    const int*   __restrict__ nei,    // [N,K]
    const float* __restrict__ w1, const float* __restrict__ g1, const float* __restrict__ b1,
    const float* __restrict__ w2, const float* __restrict__ g2, const float* __restrict__ b2,
    const float* __restrict__ w3, const float* __restrict__ g3, const float* __restrict__ b3,
    const float* __restrict__ lw,     // [96,64]
    const float* __restrict__ lb,     // [64]
    float* __restrict__ out_feat,     // [N,64]
    float* __restrict__ out_wni,      // [N,K,3]
    int n_pts)
{
    const int n = blockIdx.x * blockDim.x + threadIdx.x;
    if (n >= n_pts) return;

    const float cx = xyz[n * 3 + 0];
    const float cy = xyz[n * 3 + 1];
    const float cz = xyz[n * 3 + 2];

    // 16 neighbor indices via 4x int4 (coalesced 64B per thread region)
    int idx[K];
    {
        const int4* p = reinterpret_cast<const int4*>(nei + (size_t)n * K);
        int4 a = p[0], b = p[1], c = p[2], d = p[3];
        idx[0] = a.x; idx[1] = a.y; idx[2]  = a.z; idx[3]  = a.w;
        idx[4] = b.x; idx[5] = b.y; idx[6]  = b.z; idx[7]  = b.w;
        idx[8] = c.x; idx[9] = c.y; idx[10] = c.z; idx[11] = c.w;
        idx[12] = d.x; idx[13] = d.y; idx[14] = d.z; idx[15] = d.w;
    }

    float acc[96];
#pragma unroll
    for (int i = 0; i < 96; ++i) acc[i] = 0.f;

    float lxyz[K * 3];                 // weightNetInput buffer (static idx -> VGPRs)

#pragma unroll
    for (int k = 0; k < K; ++k) {
        const int j = idx[k];                 // static index (loop fully unrolled)
        const float nx = xyz[(size_t)j * 3 + 0];
        const float ny = xyz[(size_t)j * 3 + 1];
        const float nz = xyz[(size_t)j * 3 + 2];
        const float f0 = feats[(size_t)j * 3 + 0];
        const float f1 = feats[(size_t)j * 3 + 1];
        const float f2 = feats[(size_t)j * 3 + 2];

        const float lx = nx - cx;
        const float ly = ny - cy;
        const float lz = nz - cz;

        lxyz[k * 3 + 0] = lx;
        lxyz[k * 3 + 1] = ly;
        lxyz[k * 3 + 2] = lz;

        // WeightNet layer 1: 3 -> 8, Linear -> BN(affine) -> ReLU
        float h1[8];
#pragma unroll
        for (int o = 0; o < 8; ++o) {
            float s = lx * w1[o] + ly * w1[8 + o] + lz * w1[16 + o];
            h1[o] = fmaxf(fmaf(s, g1[o], b1[o]), 0.f);
        }
        // layer 2: 8 -> 8
        float h2[8];
#pragma unroll
        for (int o = 0; o < 8; ++o) {
            float s = 0.f;
#pragma unroll
            for (int i = 0; i < 8; ++i) s = fmaf(h1[i], w2[i * 8 + o], s);
            h2[o] = fmaxf(fmaf(s, g2[o], b2[o]), 0.f);
        }
        // layer 3: 8 -> 16
        float h3[16];
#pragma unroll
        for (int o = 0; o < 16; ++o) {
            float s = 0.f;
#pragma unroll
            for (int i = 0; i < 8; ++i) s = fmaf(h2[i], w3[i * 16 + o], s);
            h3[o] = fmaxf(fmaf(s, g3[o], b3[o]), 0.f);
        }

        // acc[c][w] += cval[c] * h3[w]; channel order: feats(3) then coords(3)
        const float c0 = f0, c1 = f1, c2 = f2, c3 = lx, c4 = ly, c5 = lz;
#pragma unroll
        for (int w = 0; w < 16; ++w) {
            const float h = h3[w];
            acc[0 * 16 + w] = fmaf(c0, h, acc[0 * 16 + w]);
            acc[1 * 16 + w] = fmaf(c1, h, acc[1 * 16 + w]);
            acc[2 * 16 + w] = fmaf(c2, h, acc[2 * 16 + w]);
            acc[3 * 16 + w] = fmaf(c3, h, acc[3 * 16 + w]);
            acc[4 * 16 + w] = fmaf(c4, h, acc[4 * 16 + w]);
            acc[5 * 16 + w] = fmaf(c5, h, acc[5 * 16 + w]);
        }
    }

    // weightNetInput: 48 floats = 12x 16B nt-stores, contiguous per thread
    {
        f32x4* wp = reinterpret_cast<f32x4*>(out_wni + (size_t)n * (K * 3));
#pragma unroll
        for (int t = 0; t < 12; ++t) {
            f32x4 v = { lxyz[4 * t + 0], lxyz[4 * t + 1],
                        lxyz[4 * t + 2], lxyz[4 * t + 3] };
            __builtin_nontemporal_store(v, wp + t);
        }
    }

    // Final linear: out[o] = relu(lb[o] + sum_j acc[j] * lw[j*64+o]),
    // chunked over o in groups of 16 to bound live registers.
#pragma unroll 1
    for (int ch = 0; ch < 4; ++ch) {
        const int o0 = ch * 16;
        float o16[16];
#pragma unroll
        for (int t = 0; t < 16; ++t) o16[t] = lb[o0 + t];
#pragma unroll
        for (int j2 = 0; j2 < 96; ++j2) {     // static acc index (fully unrolled)
            const float a = acc[j2];
#pragma unroll
            for (int t = 0; t < 16; ++t)
                o16[t] = fmaf(a, lw[(size_t)j2 * 64 + o0 + t], o16[t]);
        }
        f32x4* op = reinterpret_cast<f32x4*>(out_feat + (size_t)n * 64 + o0);
#pragma unroll
        for (int t = 0; t < 4; ++t) {
            f32x4 v = { fmaxf(o16[4 * t + 0], 0.f),
                        fmaxf(o16[4 * t + 1], 0.f),
                        fmaxf(o16[4 * t + 2], 0.f),
                        fmaxf(o16[4 * t + 3], 0.f) };
            __builtin_nontemporal_store(v, op + t);
        }
    }
}

extern "C" void kernel_launch(void* const* d_in, const int* in_sizes, int n_in,
                              void* d_out, int out_size, void* d_ws, size_t ws_size,
                              hipStream_t stream) {
    const float* xyz   = (const float*)d_in[0];
    const float* feats = (const float*)d_in[1];
    const int*   nei   = (const int*)d_in[2];
    const float* w1 = (const float*)d_in[3];
    const float* g1 = (const float*)d_in[4];
    const float* b1 = (const float*)d_in[5];
    const float* w2 = (const float*)d_in[6];
    const float* g2 = (const float*)d_in[7];
    const float* b2 = (const float*)d_in[8];
    const float* w3 = (const float*)d_in[9];
    const float* g3 = (const float*)d_in[10];
    const float* b3 = (const float*)d_in[11];
    const float* lw = (const float*)d_in[12];
    const float* lb = (const float*)d_in[13];

    const int n_pts = in_sizes[0] / 3;              // xyz is [N,3]

    float* out = (float*)d_out;
    float* out_feat = out;                          // [N,64] first in return order
    float* out_wni  = out + (size_t)n_pts * C_OUT;  // then [N,K,3]

    const int threads = 256;
    const int blocks  = (n_pts + threads - 1) / threads;
    pointconv_fused<<<blocks, threads, 0, stream>>>(
        xyz, feats, nei,
        w1, g1, b1, w2, g2, b2, w3, g3, b3,
        lw, lb, out_feat, out_wni, n_pts);
}

// Round 11
// 352.426 us; speedup vs baseline: 1.1905x; 1.1905x over previous
//
#include <hip/hip_runtime.h>

// PointConv fused kernel for MI355X (gfx950).
// B=1, N=200000, K=16, C_IN=3, C_MID=16, HIDDEN=[8,8], LAST_CH=6, C_OUT=64.
// One thread per point: gather 16 neighbors, WeightNet (3->8->8->16, BN folded),
// acc[96] outer-product accumulate, final 96x64 linear + ReLU.
// R7 baseline: 311 us, VALUBusy 44%, HBM 14%, WRITE 239 MB (2.67x ideal),
//              FETCH 98 MB, VGPR 128, occupancy 17.7% (grid-limited).
// R8: (a) REVERT R2 nt-stores — measured 2.67x write amplification + RMW
//         fetches from partial-line eviction (per-lane stride 192/256 B means
//         each wave store touches 64 lines; nt evicts before merge).
//     (b) Stage lw (24 KB) + lb in LDS per block — kills the per-wave 24 KB
//         s_load streaming (SGPR-bounded batches serialized on lgkmcnt) that
//         stalled the final linear. LDS reads are uniform-address broadcasts.
// R9-R11: resubmissions of R8 unchanged (broker timeouts / container failure;
//         R8 has never been measured).

constexpr int K     = 16;
constexpr int C_OUT = 64;
constexpr int ACC   = 96;   // LAST_CH(6) * C_MID(16)

typedef float f32x4 __attribute__((ext_vector_type(4)));

__global__ __launch_bounds__(256, 2) void pointconv_fused(
    const float* __restrict__ xyz,    // [N,3]
    const float* __restrict__ feats,  // [N,3]
    const int*   __restrict__ nei,    // [N,K]
    const float* __restrict__ w1, const float* __restrict__ g1, const float* __restrict__ b1,
    const float* __restrict__ w2, const float* __restrict__ g2, const float* __restrict__ b2,
    const float* __restrict__ w3, const float* __restrict__ g3, const float* __restrict__ b3,
    const float* __restrict__ lw,     // [96,64]
    const float* __restrict__ lb,     // [64]
    float* __restrict__ out_feat,     // [N,64]
    float* __restrict__ out_wni,      // [N,K,3]
    int n_pts)
{
    __shared__ float slw[ACC * C_OUT];   // 24 KB
    __shared__ float slb[C_OUT];         // 256 B

    const int tid = threadIdx.x;

    // Cooperative staging of final-linear weights (before any early-out so the
    // 64-valid-thread tail block still reaches the barrier with all threads).
    {
        const f32x4* src = reinterpret_cast<const f32x4*>(lw);
        f32x4*       dst = reinterpret_cast<f32x4*>(slw);
#pragma unroll
        for (int i = 0; i < (ACC * C_OUT / 4) / 256; ++i)   // 1536/256 = 6
            dst[tid + i * 256] = src[tid + i * 256];
        if (tid < C_OUT / 4)
            reinterpret_cast<f32x4*>(slb)[tid] =
                reinterpret_cast<const f32x4*>(lb)[tid];
    }
    __syncthreads();

    const int n = blockIdx.x * blockDim.x + tid;
    if (n >= n_pts) return;

    const float cx = xyz[n * 3 + 0];
    const float cy = xyz[n * 3 + 1];
    const float cz = xyz[n * 3 + 2];

    // 16 neighbor indices via 4x int4 (coalesced 64B per thread region)
    int idx[K];
    {
        const int4* p = reinterpret_cast<const int4*>(nei + (size_t)n * K);
        int4 a = p[0], b = p[1], c = p[2], d = p[3];
        idx[0] = a.x; idx[1] = a.y; idx[2]  = a.z; idx[3]  = a.w;
        idx[4] = b.x; idx[5] = b.y; idx[6]  = b.z; idx[7]  = b.w;
        idx[8] = c.x; idx[9] = c.y; idx[10] = c.z; idx[11] = c.w;
        idx[12] = d.x; idx[13] = d.y; idx[14] = d.z; idx[15] = d.w;
    }

    float acc[ACC];
#pragma unroll
    for (int i = 0; i < ACC; ++i) acc[i] = 0.f;

    float lxyz[K * 3];                 // weightNetInput buffer (static idx -> VGPRs)

#pragma unroll
    for (int k = 0; k < K; ++k) {
        const int j = idx[k];                 // static index (loop fully unrolled)
        const float nx = xyz[(size_t)j * 3 + 0];
        const float ny = xyz[(size_t)j * 3 + 1];
        const float nz = xyz[(size_t)j * 3 + 2];
        const float f0 = feats[(size_t)j * 3 + 0];
        const float f1 = feats[(size_t)j * 3 + 1];
        const float f2 = feats[(size_t)j * 3 + 2];

        const float lx = nx - cx;
        const float ly = ny - cy;
        const float lz = nz - cz;

        lxyz[k * 3 + 0] = lx;
        lxyz[k * 3 + 1] = ly;
        lxyz[k * 3 + 2] = lz;

        // WeightNet layer 1: 3 -> 8, Linear -> BN(affine) -> ReLU
        float h1[8];
#pragma unroll
        for (int o = 0; o < 8; ++o) {
            float s = lx * w1[o] + ly * w1[8 + o] + lz * w1[16 + o];
            h1[o] = fmaxf(fmaf(s, g1[o], b1[o]), 0.f);
        }
        // layer 2: 8 -> 8
        float h2[8];
#pragma unroll
        for (int o = 0; o < 8; ++o) {
            float s = 0.f;
#pragma unroll
            for (int i = 0; i < 8; ++i) s = fmaf(h1[i], w2[i * 8 + o], s);
            h2[o] = fmaxf(fmaf(s, g2[o], b2[o]), 0.f);
        }
        // layer 3: 8 -> 16
        float h3[16];
#pragma unroll
        for (int o = 0; o < 16; ++o) {
            float s = 0.f;
#pragma unroll
            for (int i = 0; i < 8; ++i) s = fmaf(h2[i], w3[i * 16 + o], s);
            h3[o] = fmaxf(fmaf(s, g3[o], b3[o]), 0.f);
        }

        // acc[c][w] += cval[c] * h3[w]; channel order: feats(3) then coords(3)
        const float c0 = f0, c1 = f1, c2 = f2, c3 = lx, c4 = ly, c5 = lz;
#pragma unroll
        for (int w = 0; w < 16; ++w) {
            const float h = h3[w];
            acc[0 * 16 + w] = fmaf(c0, h, acc[0 * 16 + w]);
            acc[1 * 16 + w] = fmaf(c1, h, acc[1 * 16 + w]);
            acc[2 * 16 + w] = fmaf(c2, h, acc[2 * 16 + w]);
            acc[3 * 16 + w] = fmaf(c3, h, acc[3 * 16 + w]);
            acc[4 * 16 + w] = fmaf(c4, h, acc[4 * 16 + w]);
            acc[5 * 16 + w] = fmaf(c5, h, acc[5 * 16 + w]);
        }
    }

    // weightNetInput: 48 floats = 12x 16B plain stores, contiguous per thread
    {
        f32x4* wp = reinterpret_cast<f32x4*>(out_wni + (size_t)n * (K * 3));
#pragma unroll
        for (int t = 0; t < 12; ++t) {
            f32x4 v = { lxyz[4 * t + 0], lxyz[4 * t + 1],
                        lxyz[4 * t + 2], lxyz[4 * t + 3] };
            wp[t] = v;
        }
    }

    // Final linear from LDS: out[o] = relu(slb[o] + sum_j acc[j]*slw[j*64+o]),
    // chunked over o in groups of 16. All lanes read the same LDS address ->
    // broadcast, bank-conflict-free, deep ds_read pipelining.
#pragma unroll 1
    for (int ch = 0; ch < 4; ++ch) {
        const int o0 = ch * 16;
        float o16[16];
#pragma unroll
        for (int t = 0; t < 16; ++t) o16[t] = slb[o0 + t];
#pragma unroll
        for (int j2 = 0; j2 < ACC; ++j2) {    // static acc index (fully unrolled)
            const float a = acc[j2];
#pragma unroll
            for (int t = 0; t < 16; ++t)
                o16[t] = fmaf(a, slw[j2 * C_OUT + o0 + t], o16[t]);
        }
        f32x4* op = reinterpret_cast<f32x4*>(out_feat + (size_t)n * 64 + o0);
#pragma unroll
        for (int t = 0; t < 4; ++t) {
            f32x4 v = { fmaxf(o16[4 * t + 0], 0.f),
                        fmaxf(o16[4 * t + 1], 0.f),
                        fmaxf(o16[4 * t + 2], 0.f),
                        fmaxf(o16[4 * t + 3], 0.f) };
            op[t] = v;
        }
    }
}

extern "C" void kernel_launch(void* const* d_in, const int* in_sizes, int n_in,
                              void* d_out, int out_size, void* d_ws, size_t ws_size,
                              hipStream_t stream) {
    const float* xyz   = (const float*)d_in[0];
    const float* feats = (const float*)d_in[1];
    const int*   nei   = (const int*)d_in[2];
    const float* w1 = (const float*)d_in[3];
    const float* g1 = (const float*)d_in[4];
    const float* b1 = (const float*)d_in[5];
    const float* w2 = (const float*)d_in[6];
    const float* g2 = (const float*)d_in[7];
    const float* b2 = (const float*)d_in[8];
    const float* w3 = (const float*)d_in[9];
    const float* g3 = (const float*)d_in[10];
    const float* b3 = (const float*)d_in[11];
    const float* lw = (const float*)d_in[12];
    const float* lb = (const float*)d_in[13];

    const int n_pts = in_sizes[0] / 3;              // xyz is [N,3]

    float* out = (float*)d_out;
    float* out_feat = out;                          // [N,64] first in return order
    float* out_wni  = out + (size_t)n_pts * C_OUT;  // then [N,K,3]

    const int threads = 256;
    const int blocks  = (n_pts + threads - 1) / threads;
    pointconv_fused<<<blocks, threads, 0, stream>>>(
        xyz, feats, nei,
        w1, g1, b1, w2, g2, b2, w3, g3, b3,
        lw, lb, out_feat, out_wni, n_pts);
}